// Round 8
// baseline (172.369 us; speedup 1.0000x reference)
//
#include <hip/hip_runtime.h>
#include <hip/hip_bf16.h>

typedef unsigned short u16;
typedef float  f32x4  __attribute__((ext_vector_type(4)));
typedef __bf16 bf16x8 __attribute__((ext_vector_type(8)));
typedef unsigned short u16x8 __attribute__((ext_vector_type(8)));
typedef unsigned short u16x4 __attribute__((ext_vector_type(4)));

__device__ __forceinline__ u16 f2bfu(float f) {
    __hip_bfloat16 h = __float2bfloat16(f);
    return __builtin_bit_cast(unsigned short, h);
}

constexpr int kHW = 196;   // 14*14
constexpr int kKC = 25;    // ceil(196/8) k-chunks
constexpr int kLC = 25;    // ceil(196/8) l-chunks
constexpr int kChunks = kKC * kLC;  // 625 per batch

// ---------------- fused prep: pw transpose + w2/w3 interleave ----------------
// blocks 0..31: transpose pw [256][512] -> pwT [512][256] (64x64 tiles)
// blocks 32..287: w2 -> w2i [kk][kg][n][k8]; 288..543: w3 -> w3i
__global__ __launch_bounds__(256)
void k_prep(const float* __restrict__ pw, float* __restrict__ pwT,
            const float* __restrict__ w2, u16* __restrict__ w2i,
            const float* __restrict__ w3, u16* __restrict__ w3i) {
    int id = blockIdx.x;
    if (id < 32) {
        __shared__ float t[64][65];
        int c0 = (id & 7) * 64, r0 = (id >> 3) * 64;
        int lc = threadIdx.x & 63, lg = threadIdx.x >> 6;
#pragma unroll
        for (int rr = 0; rr < 16; ++rr) {
            int r = lg * 16 + rr;
            t[r][lc] = pw[(r0 + r) * 512 + c0 + lc];
        }
        __syncthreads();
#pragma unroll
        for (int rr = 0; rr < 16; ++rr) {
            int r = lg * 16 + rr;
            pwT[(c0 + r) * 256 + r0 + lc] = t[lc][r];
        }
    } else {
        const float* in = (id < 288) ? w2 : w3;
        u16* out = (id < 288) ? w2i : w3i;
        int k = (id < 288) ? id - 32 : id - 288;
        int n = threadIdx.x;
        int kk = k >> 5, kg = (k >> 3) & 3, k8 = k & 7;
        out[(((((kk << 2) + kg) << 8) + n) << 3) + k8] = f2bfu(in[(k << 8) + n]);
    }
}

// ---------------- fused xf + al/ak: grid (49, 8), 256 thr, 4 p's/block --------
// Each thread owns one channel c for 4 positions: no cross-thread reduction.
__global__ __launch_bounds__(256)
void k_xa2(const float* __restrict__ im, const float* __restrict__ pwT,
           const float* __restrict__ pb, const float* __restrict__ w1,
           float* __restrict__ al, float* __restrict__ ak) {
    __shared__ float sm[512 * 4];   // im slice [i][pi]
    __shared__ float smx[256 * 4];  // xf [k][pi]
    const int tid = threadIdx.x;
    const int b = blockIdx.y;
    const int p0 = blockIdx.x * 4;  // 49*4 = 196 exact
#pragma unroll
    for (int it = 0; it < 8; ++it) {
        int idx = it * 256 + tid;
        int i = idx >> 2, pi = idx & 3;
        sm[idx] = im[(b * 512 + i) * kHW + p0 + pi];
    }
    __syncthreads();
    const int c = tid;
    float acc[4] = {};
    for (int k = 0; k < 512; ++k) {
        float w = pwT[(k << 8) + c];
        f32x4 x = *(const f32x4*)&sm[k * 4];
#pragma unroll
        for (int j = 0; j < 4; ++j) acc[j] += x[j] * w;
    }
    float bias = pb[c];
#pragma unroll
    for (int j = 0; j < 4; ++j) smx[c * 4 + j] = acc[j] + bias;
    __syncthreads();
    float a2l[4] = {}, a2k[4] = {};
    const float* w1k = w1 + 256 * 256;
    for (int k = 0; k < 256; ++k) {
        float wl = w1[(k << 8) + c];
        float wk = w1k[(k << 8) + c];
        f32x4 x = *(const f32x4*)&smx[k * 4];
#pragma unroll
        for (int j = 0; j < 4; ++j) { a2l[j] += x[j] * wl; a2k[j] += x[j] * wk; }
    }
#pragma unroll
    for (int pi = 0; pi < 4; ++pi) {
        al[((b * kHW + p0 + pi) << 8) + c] = a2l[pi];
        ak[((b * kHW + p0 + pi) << 8) + c] = a2k[pi];
    }
}

// ---------------- main fused pair kernel v7 = v6 + raw LDS staging ----------------
// grid (25 lc, 25 kc, 8 b) = 5000 blocks, block 256 (4 waves; wave = ch quarter).
// Tile: (8 k x 8 l) = 64 pairs x 256 ch. LDS 48KB -> 3 blocks/CU.
__global__ __launch_bounds__(256, 3)
void k_main7(const float* __restrict__ ak, const float* __restrict__ al,
             const float* __restrict__ b1, const u16* __restrict__ w2i,
             const float* __restrict__ b2, const u16* __restrict__ w3i,
             const float* __restrict__ b3, float* __restrict__ part) {
    __shared__ u16 smem[64 * 256];   // 32 KB: h1, then h2 in-place
    __shared__ float raw[16 * 256];  // 16 KB: 8 ak rows then 8 al rows (fp32)
    const int tid = threadIdx.x;
    const int lc = blockIdx.x, kc = blockIdx.y, b = blockIdx.z;
    const int k0 = kc * 8, l0 = lc * 8;

    // ---- raw stage: 16 source rows global -> LDS (each read ONCE) ----
    {
        int r = tid >> 4;       // 0..15
        int t = tid & 15;       // 16 threads per row
        int src_row = (r < 8) ? (k0 + r) : (l0 + (r - 8));
        if (src_row > 195) src_row = 195;
        const float* src = ((r < 8) ? ak : al) + ((b * kHW + src_row) << 8);
#pragma unroll
        for (int j = 0; j < 4; ++j)
            *(f32x4*)&raw[r * 256 + j * 64 + t * 4] = *(const f32x4*)(src + j * 64 + t * 4);
    }
    __syncthreads();

    // ---- build h1 = relu(ak[k] + al[l] + b1) -> bf16 LDS [pair][ch], swizzled ----
    {
        const int cc = tid & 31;          // 8-ch group, fixed per thread
        f32x4 c0v = *(const f32x4*)(b1 + (cc << 3));
        f32x4 c1v = *(const f32x4*)(b1 + (cc << 3) + 4);
#pragma unroll
        for (int it = 0; it < 8; ++it) {
            int row = (it * 256 + tid) >> 5;  // 0..63
            const float* akp = &raw[(row >> 3) * 256 + (cc << 3)];
            const float* alp = &raw[(8 + (row & 7)) * 256 + (cc << 3)];
            f32x4 k0v = *(const f32x4*)akp;
            f32x4 k1v = *(const f32x4*)(akp + 4);
            f32x4 l0v = *(const f32x4*)alp;
            f32x4 l1v = *(const f32x4*)(alp + 4);
            u16x8 v;
#pragma unroll
            for (int j = 0; j < 4; ++j) {
                v[j]     = f2bfu(fmaxf(k0v[j] + l0v[j] + c0v[j], 0.f));
                v[4 + j] = f2bfu(fmaxf(k1v[j] + l1v[j] + c1v[j], 0.f));
            }
            int byte = (row << 9) + (cc << 4);
            byte ^= (row & 7) << 4;
            *(u16x8*)((char*)smem + byte) = v;
        }
    }
    __syncthreads();

    const int lane = tid & 63;
    const int wn = tid >> 6;   // wave = ch quarter 0..3
    const int l15 = lane & 15;
    const int kg = lane >> 4;  // 0..3

    f32x4 acc[4][4];  // [fn ch-frag][fm pair-frag], reused for both GEMMs
    const int wbase = (wn * 64 + l15) << 3;

    // ---- GEMM1: h2^T = w2 x h1^T ----
#pragma unroll
    for (int fn = 0; fn < 4; ++fn)
#pragma unroll
        for (int fm = 0; fm < 4; ++fm) acc[fn][fm] = f32x4{0.f, 0.f, 0.f, 0.f};
    for (int kk = 0; kk < 8; ++kk) {
        int kb = kk * 32 + kg * 8;
        bf16x8 hb[4];
#pragma unroll
        for (int fm = 0; fm < 4; ++fm) {
            int row = fm * 16 + l15;
            int byte = (row << 9) + (kb << 1);
            byte ^= (row & 7) << 4;
            hb[fm] = __builtin_bit_cast(bf16x8, *(const u16x8*)((const char*)smem + byte));
        }
        const u16* wp = w2i + ((((kk << 2) + kg) << 11) + wbase);
#pragma unroll
        for (int fn = 0; fn < 4; ++fn) {
            bf16x8 aw = __builtin_bit_cast(bf16x8, *(const u16x8*)(wp + (fn << 7)));
#pragma unroll
            for (int fm = 0; fm < 4; ++fm)
                acc[fn][fm] = __builtin_amdgcn_mfma_f32_16x16x32_bf16(aw, hb[fm], acc[fn][fm], 0, 0, 0);
        }
    }
    __syncthreads();

    // ---- epilogue: h2 = relu(D1 + b2) -> bf16 LDS, packed 8B writes ----
#pragma unroll
    for (int fn = 0; fn < 4; ++fn) {
        f32x4 b2v = *(const f32x4*)(b2 + wn * 64 + fn * 16 + kg * 4);
#pragma unroll
        for (int fm = 0; fm < 4; ++fm) {
            int prow = fm * 16 + l15;
            u16x4 pv;
#pragma unroll
            for (int r = 0; r < 4; ++r)
                pv[r] = f2bfu(fmaxf(acc[fn][fm][r] + b2v[r], 0.f));
            int byte = (prow << 9) + ((wn * 64 + fn * 16 + kg * 4) << 1);
            byte ^= (prow & 7) << 4;
            *(u16x4*)((char*)smem + byte) = pv;
        }
    }
    __syncthreads();

    // ---- GEMM2: h3^T = w3 x h2^T ----
#pragma unroll
    for (int fn = 0; fn < 4; ++fn)
#pragma unroll
        for (int fm = 0; fm < 4; ++fm) acc[fn][fm] = f32x4{0.f, 0.f, 0.f, 0.f};
    for (int kk = 0; kk < 8; ++kk) {
        int kb = kk * 32 + kg * 8;
        bf16x8 hb[4];
#pragma unroll
        for (int fm = 0; fm < 4; ++fm) {
            int row = fm * 16 + l15;
            int byte = (row << 9) + (kb << 1);
            byte ^= (row & 7) << 4;
            hb[fm] = __builtin_bit_cast(bf16x8, *(const u16x8*)((const char*)smem + byte));
        }
        const u16* wp = w3i + ((((kk << 2) + kg) << 11) + wbase);
#pragma unroll
        for (int fn = 0; fn < 4; ++fn) {
            bf16x8 aw = __builtin_bit_cast(bf16x8, *(const u16x8*)(wp + (fn << 7)));
#pragma unroll
            for (int fm = 0; fm < 4; ++fm)
                acc[fn][fm] = __builtin_amdgcn_mfma_f32_16x16x32_bf16(aw, hb[fm], acc[fn][fm], 0, 0, 0);
        }
    }

    // ---- masked col-sum + wave reduce + direct store to part ----
    float s[4][4] = {};
#pragma unroll
    for (int fm = 0; fm < 4; ++fm) {
        int pr = fm * 16 + l15;
        int ki = k0 + (pr >> 3);
        int li = l0 + (pr & 7);
        float vm = (ki < kHW && li < kHW) ? 1.f : 0.f;
#pragma unroll
        for (int fn = 0; fn < 4; ++fn) {
            f32x4 b3v = *(const f32x4*)(b3 + wn * 64 + fn * 16 + kg * 4);
#pragma unroll
            for (int r = 0; r < 4; ++r)
                s[fn][r] += vm * fmaxf(acc[fn][fm][r] + b3v[r], 0.f);
        }
    }
#pragma unroll
    for (int fn = 0; fn < 4; ++fn)
#pragma unroll
        for (int r = 0; r < 4; ++r) {
            s[fn][r] += __shfl_xor(s[fn][r], 1);
            s[fn][r] += __shfl_xor(s[fn][r], 2);
            s[fn][r] += __shfl_xor(s[fn][r], 4);
            s[fn][r] += __shfl_xor(s[fn][r], 8);
        }
    if (l15 == 0) {
        int chunkid = (b * kKC + kc) * kLC + lc;
        float* pp = part + chunkid * 256 + wn * 64 + kg * 4;
#pragma unroll
        for (int fn = 0; fn < 4; ++fn)
            *(f32x4*)(pp + fn * 16) = f32x4{s[fn][0], s[fn][1], s[fn][2], s[fn][3]};
    }
}

// ---------------- final reduce over 625 chunks per batch ----------------
__global__ __launch_bounds__(1024)
void k_reduce(const float* __restrict__ part, float* __restrict__ out) {
    __shared__ float red[4][256];
    int b = blockIdx.x;
    int c = threadIdx.x & 255;
    int stripe = threadIdx.x >> 8;
    const float* p = part + (b * kChunks) * 256 + c;
    float s = 0.f;
    for (int j = stripe; j < kChunks; j += 4) s += p[j * 256];
    red[stripe][c] = s;
    __syncthreads();
    if (threadIdx.x < 256)
        out[b * 256 + threadIdx.x] = red[0][threadIdx.x] + red[1][threadIdx.x] +
                                     red[2][threadIdx.x] + red[3][threadIdx.x];
}

extern "C" void kernel_launch(void* const* d_in, const int* in_sizes, int n_in,
                              void* d_out, int out_size, void* d_ws, size_t ws_size,
                              hipStream_t stream) {
    const float* im = (const float*)d_in[0];
    const float* pw = (const float*)d_in[3];
    const float* pb = (const float*)d_in[4];
    const float* w1 = (const float*)d_in[5];
    const float* b1 = (const float*)d_in[6];
    const float* w2 = (const float*)d_in[7];
    const float* b2 = (const float*)d_in[8];
    const float* w3 = (const float*)d_in[9];
    const float* b3 = (const float*)d_in[10];
    float* out = (float*)d_out;

    float* al  = (float*)d_ws;            // 8*196*256
    float* ak  = al + 8 * 196 * 256;
    float* pwT = ak + 8 * 196 * 256;      // [512][256]
    u16* w2i = (u16*)(pwT + 512 * 256);   // [8kk][4kg][256ch][8k] bf16
    u16* w3i = w2i + 256 * 256;
    float* part = (float*)(w3i + 256 * 256);  // [8*625][256] = 5.12 MB

    hipLaunchKernelGGL(k_prep, dim3(544), dim3(256), 0, stream, pw, pwT, w2, w2i, w3, w3i);
    hipLaunchKernelGGL(k_xa2, dim3(49, 8), dim3(256), 0, stream, im, pwT, pb, w1, al, ak);
    hipLaunchKernelGGL(k_main7, dim3(kLC, kKC, 8), dim3(256), 0, stream,
                       ak, al, b1, w2i, b2, w3i, b3, part);
    hipLaunchKernelGGL(k_reduce, dim3(8), dim3(1024), 0, stream, part, out);
}

// Round 9
// 151.651 us; speedup vs baseline: 1.1366x; 1.1366x over previous
//
#include <hip/hip_runtime.h>
#include <hip/hip_bf16.h>

typedef unsigned short u16;
typedef float  f32x4  __attribute__((ext_vector_type(4)));
typedef __bf16 bf16x8 __attribute__((ext_vector_type(8)));
typedef unsigned short u16x8 __attribute__((ext_vector_type(8)));
typedef unsigned short u16x4 __attribute__((ext_vector_type(4)));

__device__ __forceinline__ u16 f2bfu(float f) {
    __hip_bfloat16 h = __float2bfloat16(f);
    return __builtin_bit_cast(unsigned short, h);
}

constexpr int kHW = 196;   // 14*14
constexpr int kKC = 25;    // ceil(196/8) k-chunks
constexpr int kLC = 25;    // ceil(196/8) l-chunks
constexpr int kChunks = kKC * kLC;  // 625 per batch

// ---------------- prep: interleave ALL weights to [kk][kg][n][k8] bf16 ----------------
// pwi: from pw [256 n][512 k] (K=512, 16 kk); w1li/w1ki: from w1 [512 k][256 n]
// (first/second 256 k rows); w2i/w3i: from w2/w3 [256 k][256 n].
__global__ __launch_bounds__(256)
void k_prep(const float* __restrict__ pw, u16* __restrict__ pwi,
            const float* __restrict__ w1, u16* __restrict__ w1li, u16* __restrict__ w1ki,
            const float* __restrict__ w2, u16* __restrict__ w2i,
            const float* __restrict__ w3, u16* __restrict__ w3i) {
    int id = blockIdx.x;
    int n = threadIdx.x;
    if (id < 512) {
        int k = id;
        int kk = k >> 5, kg = (k >> 3) & 3, k8 = k & 7;
        pwi[(((((kk << 2) + kg) << 8) + n) << 3) + k8] = f2bfu(pw[n * 512 + k]);
    } else {
        int k = (id - 512) & 255;
        int kk = k >> 5, kg = (k >> 3) & 3, k8 = k & 7;
        int idx = (((((kk << 2) + kg) << 8) + n) << 3) + k8;
        if (id < 768)       w1li[idx] = f2bfu(w1[k * 256 + n]);
        else if (id < 1024) w1ki[idx] = f2bfu(w1[(k + 256) * 256 + n]);
        else if (id < 1280) w2i[idx]  = f2bfu(w2[k * 256 + n]);
        else                w3i[idx]  = f2bfu(w3[k * 256 + n]);
    }
}

// ---------------- MFMA prologue: xf then al/ak. grid (14, 8), 256 thr ----------------
// Block: 14 p's (16 slots, clamped). GEMM1: xf[c][p] = pw x imT (K=512).
// GEMM2 (x2): al/ak[n][p] = w1l/w1k x xf (K=256). Stores fp32 al/ak[p][n].
__global__ __launch_bounds__(256, 2)
void k_xa3(const float* __restrict__ im, const u16* __restrict__ pwi,
           const float* __restrict__ pb, const u16* __restrict__ w1li,
           const u16* __restrict__ w1ki, float* __restrict__ al,
           float* __restrict__ ak) {
    __shared__ u16 imT[16 * 512];   // [p][i] bf16, swizzled rows (1KB), 16KB
    __shared__ u16 xfs[16 * 256];   // [p][c] bf16, swizzled rows (512B), 8KB
    const int tid = threadIdx.x;
    const int b = blockIdx.y;
    const int p0 = blockIdx.x * 14;

    // ---- stage imT[p][i] = bf16(im[b][i][p0+p]) ----
    {
        int t4 = tid & 3;       // p-quarter
        int ibase = tid >> 2;   // 0..63
#pragma unroll
        for (int it = 0; it < 8; ++it) {
            int i = it * 64 + ibase;
            const float* src = im + (b * 512 + i) * kHW;
#pragma unroll
            for (int j = 0; j < 4; ++j) {
                int prow = t4 * 4 + j;
                int p = p0 + prow; if (p > 195) p = 195;
                int byte = (prow << 10) + (i << 1);
                byte ^= (prow & 7) << 4;
                *(u16*)((char*)imT + byte) = f2bfu(src[p]);
            }
        }
    }
    __syncthreads();

    const int lane = tid & 63;
    const int wn = tid >> 6;   // wave = ch quarter
    const int l15 = lane & 15;
    const int kg = lane >> 4;
    const int wbase = (wn * 64 + l15) << 3;

    // ---- GEMM1: xf^T[c][p] = pw x im^T, K=512 ----
    f32x4 acc[4];
#pragma unroll
    for (int fn = 0; fn < 4; ++fn) acc[fn] = f32x4{0.f, 0.f, 0.f, 0.f};
    for (int kk = 0; kk < 16; ++kk) {
        int kb = kk * 32 + kg * 8;
        int byte = (l15 << 10) + (kb << 1);
        byte ^= (l15 & 7) << 4;
        bf16x8 hb = __builtin_bit_cast(bf16x8, *(const u16x8*)((const char*)imT + byte));
        const u16* wp = pwi + ((((kk << 2) + kg) << 11) + wbase);
#pragma unroll
        for (int fn = 0; fn < 4; ++fn) {
            bf16x8 aw = __builtin_bit_cast(bf16x8, *(const u16x8*)(wp + (fn << 7)));
            acc[fn] = __builtin_amdgcn_mfma_f32_16x16x32_bf16(aw, hb, acc[fn], 0, 0, 0);
        }
    }
    // epilogue: xf = acc + pb -> bf16 xfs[p][c]
#pragma unroll
    for (int fn = 0; fn < 4; ++fn) {
        f32x4 pbv = *(const f32x4*)(pb + wn * 64 + fn * 16 + kg * 4);
        u16x4 pv;
#pragma unroll
        for (int r = 0; r < 4; ++r) pv[r] = f2bfu(acc[fn][r] + pbv[r]);
        int byte = (l15 << 9) + ((wn * 64 + fn * 16 + kg * 4) << 1);
        byte ^= (l15 & 7) << 4;
        *(u16x4*)((char*)xfs + byte) = pv;
    }
    __syncthreads();

    // ---- GEMM2 x2: al / ak (K=256), store fp32 [p][n] ----
    const int p = p0 + l15;
    const bool valid = (l15 < 14) && (p < kHW);
#pragma unroll
    for (int sel = 0; sel < 2; ++sel) {
        const u16* wsrc = sel ? w1ki : w1li;
        f32x4 a2[4];
#pragma unroll
        for (int fn = 0; fn < 4; ++fn) a2[fn] = f32x4{0.f, 0.f, 0.f, 0.f};
        for (int kk = 0; kk < 8; ++kk) {
            int kb = kk * 32 + kg * 8;
            int byte = (l15 << 9) + (kb << 1);
            byte ^= (l15 & 7) << 4;
            bf16x8 hb = __builtin_bit_cast(bf16x8, *(const u16x8*)((const char*)xfs + byte));
            const u16* wp = wsrc + ((((kk << 2) + kg) << 11) + wbase);
#pragma unroll
            for (int fn = 0; fn < 4; ++fn) {
                bf16x8 aw = __builtin_bit_cast(bf16x8, *(const u16x8*)(wp + (fn << 7)));
                a2[fn] = __builtin_amdgcn_mfma_f32_16x16x32_bf16(aw, hb, a2[fn], 0, 0, 0);
            }
        }
        if (valid) {
            float* dst = (sel ? ak : al) + ((b * kHW + p) << 8) + wn * 64 + kg * 4;
#pragma unroll
            for (int fn = 0; fn < 4; ++fn) *(f32x4*)(dst + fn * 16) = a2[fn];
        }
    }
}

// ---------------- main fused pair kernel (unchanged from R7) ----------------
__global__ __launch_bounds__(256, 3)
void k_main7(const float* __restrict__ ak, const float* __restrict__ al,
             const float* __restrict__ b1, const u16* __restrict__ w2i,
             const float* __restrict__ b2, const u16* __restrict__ w3i,
             const float* __restrict__ b3, float* __restrict__ part) {
    __shared__ u16 smem[64 * 256];   // 32 KB: h1, then h2 in-place
    __shared__ float raw[16 * 256];  // 16 KB: 8 ak rows then 8 al rows (fp32)
    const int tid = threadIdx.x;
    const int lc = blockIdx.x, kc = blockIdx.y, b = blockIdx.z;
    const int k0 = kc * 8, l0 = lc * 8;

    {
        int r = tid >> 4;
        int t = tid & 15;
        int src_row = (r < 8) ? (k0 + r) : (l0 + (r - 8));
        if (src_row > 195) src_row = 195;
        const float* src = ((r < 8) ? ak : al) + ((b * kHW + src_row) << 8);
#pragma unroll
        for (int j = 0; j < 4; ++j)
            *(f32x4*)&raw[r * 256 + j * 64 + t * 4] = *(const f32x4*)(src + j * 64 + t * 4);
    }
    __syncthreads();

    {
        const int cc = tid & 31;
        f32x4 c0v = *(const f32x4*)(b1 + (cc << 3));
        f32x4 c1v = *(const f32x4*)(b1 + (cc << 3) + 4);
#pragma unroll
        for (int it = 0; it < 8; ++it) {
            int row = (it * 256 + tid) >> 5;
            const float* akp = &raw[(row >> 3) * 256 + (cc << 3)];
            const float* alp = &raw[(8 + (row & 7)) * 256 + (cc << 3)];
            f32x4 k0v = *(const f32x4*)akp;
            f32x4 k1v = *(const f32x4*)(akp + 4);
            f32x4 l0v = *(const f32x4*)alp;
            f32x4 l1v = *(const f32x4*)(alp + 4);
            u16x8 v;
#pragma unroll
            for (int j = 0; j < 4; ++j) {
                v[j]     = f2bfu(fmaxf(k0v[j] + l0v[j] + c0v[j], 0.f));
                v[4 + j] = f2bfu(fmaxf(k1v[j] + l1v[j] + c1v[j], 0.f));
            }
            int byte = (row << 9) + (cc << 4);
            byte ^= (row & 7) << 4;
            *(u16x8*)((char*)smem + byte) = v;
        }
    }
    __syncthreads();

    const int lane = tid & 63;
    const int wn = tid >> 6;
    const int l15 = lane & 15;
    const int kg = lane >> 4;

    f32x4 acc[4][4];
    const int wbase = (wn * 64 + l15) << 3;

#pragma unroll
    for (int fn = 0; fn < 4; ++fn)
#pragma unroll
        for (int fm = 0; fm < 4; ++fm) acc[fn][fm] = f32x4{0.f, 0.f, 0.f, 0.f};
    for (int kk = 0; kk < 8; ++kk) {
        int kb = kk * 32 + kg * 8;
        bf16x8 hb[4];
#pragma unroll
        for (int fm = 0; fm < 4; ++fm) {
            int row = fm * 16 + l15;
            int byte = (row << 9) + (kb << 1);
            byte ^= (row & 7) << 4;
            hb[fm] = __builtin_bit_cast(bf16x8, *(const u16x8*)((const char*)smem + byte));
        }
        const u16* wp = w2i + ((((kk << 2) + kg) << 11) + wbase);
#pragma unroll
        for (int fn = 0; fn < 4; ++fn) {
            bf16x8 aw = __builtin_bit_cast(bf16x8, *(const u16x8*)(wp + (fn << 7)));
#pragma unroll
            for (int fm = 0; fm < 4; ++fm)
                acc[fn][fm] = __builtin_amdgcn_mfma_f32_16x16x32_bf16(aw, hb[fm], acc[fn][fm], 0, 0, 0);
        }
    }
    __syncthreads();

#pragma unroll
    for (int fn = 0; fn < 4; ++fn) {
        f32x4 b2v = *(const f32x4*)(b2 + wn * 64 + fn * 16 + kg * 4);
#pragma unroll
        for (int fm = 0; fm < 4; ++fm) {
            int prow = fm * 16 + l15;
            u16x4 pv;
#pragma unroll
            for (int r = 0; r < 4; ++r)
                pv[r] = f2bfu(fmaxf(acc[fn][fm][r] + b2v[r], 0.f));
            int byte = (prow << 9) + ((wn * 64 + fn * 16 + kg * 4) << 1);
            byte ^= (prow & 7) << 4;
            *(u16x4*)((char*)smem + byte) = pv;
        }
    }
    __syncthreads();

#pragma unroll
    for (int fn = 0; fn < 4; ++fn)
#pragma unroll
        for (int fm = 0; fm < 4; ++fm) acc[fn][fm] = f32x4{0.f, 0.f, 0.f, 0.f};
    for (int kk = 0; kk < 8; ++kk) {
        int kb = kk * 32 + kg * 8;
        bf16x8 hb[4];
#pragma unroll
        for (int fm = 0; fm < 4; ++fm) {
            int row = fm * 16 + l15;
            int byte = (row << 9) + (kb << 1);
            byte ^= (row & 7) << 4;
            hb[fm] = __builtin_bit_cast(bf16x8, *(const u16x8*)((const char*)smem + byte));
        }
        const u16* wp = w3i + ((((kk << 2) + kg) << 11) + wbase);
#pragma unroll
        for (int fn = 0; fn < 4; ++fn) {
            bf16x8 aw = __builtin_bit_cast(bf16x8, *(const u16x8*)(wp + (fn << 7)));
#pragma unroll
            for (int fm = 0; fm < 4; ++fm)
                acc[fn][fm] = __builtin_amdgcn_mfma_f32_16x16x32_bf16(aw, hb[fm], acc[fn][fm], 0, 0, 0);
        }
    }

    float s[4][4] = {};
#pragma unroll
    for (int fm = 0; fm < 4; ++fm) {
        int pr = fm * 16 + l15;
        int ki = k0 + (pr >> 3);
        int li = l0 + (pr & 7);
        float vm = (ki < kHW && li < kHW) ? 1.f : 0.f;
#pragma unroll
        for (int fn = 0; fn < 4; ++fn) {
            f32x4 b3v = *(const f32x4*)(b3 + wn * 64 + fn * 16 + kg * 4);
#pragma unroll
            for (int r = 0; r < 4; ++r)
                s[fn][r] += vm * fmaxf(acc[fn][fm][r] + b3v[r], 0.f);
        }
    }
#pragma unroll
    for (int fn = 0; fn < 4; ++fn)
#pragma unroll
        for (int r = 0; r < 4; ++r) {
            s[fn][r] += __shfl_xor(s[fn][r], 1);
            s[fn][r] += __shfl_xor(s[fn][r], 2);
            s[fn][r] += __shfl_xor(s[fn][r], 4);
            s[fn][r] += __shfl_xor(s[fn][r], 8);
        }
    if (l15 == 0) {
        int chunkid = (b * kKC + kc) * kLC + lc;
        float* pp = part + chunkid * 256 + wn * 64 + kg * 4;
#pragma unroll
        for (int fn = 0; fn < 4; ++fn)
            *(f32x4*)(pp + fn * 16) = f32x4{s[fn][0], s[fn][1], s[fn][2], s[fn][3]};
    }
}

// ---------------- final reduce over 625 chunks per batch ----------------
__global__ __launch_bounds__(1024)
void k_reduce(const float* __restrict__ part, float* __restrict__ out) {
    __shared__ float red[4][256];
    int b = blockIdx.x;
    int c = threadIdx.x & 255;
    int stripe = threadIdx.x >> 8;
    const float* p = part + (b * kChunks) * 256 + c;
    float s = 0.f;
    for (int j = stripe; j < kChunks; j += 4) s += p[j * 256];
    red[stripe][c] = s;
    __syncthreads();
    if (threadIdx.x < 256)
        out[b * 256 + threadIdx.x] = red[0][threadIdx.x] + red[1][threadIdx.x] +
                                     red[2][threadIdx.x] + red[3][threadIdx.x];
}

extern "C" void kernel_launch(void* const* d_in, const int* in_sizes, int n_in,
                              void* d_out, int out_size, void* d_ws, size_t ws_size,
                              hipStream_t stream) {
    const float* im = (const float*)d_in[0];
    const float* pw = (const float*)d_in[3];
    const float* pb = (const float*)d_in[4];
    const float* w1 = (const float*)d_in[5];
    const float* b1 = (const float*)d_in[6];
    const float* w2 = (const float*)d_in[7];
    const float* b2 = (const float*)d_in[8];
    const float* w3 = (const float*)d_in[9];
    const float* b3 = (const float*)d_in[10];
    float* out = (float*)d_out;

    float* al  = (float*)d_ws;            // 8*196*256
    float* ak  = al + 8 * 196 * 256;
    u16* pwi  = (u16*)(ak + 8 * 196 * 256);  // [16kk][4kg][256n][8k]
    u16* w1li = pwi + 512 * 256;             // [8kk][4kg][256n][8k]
    u16* w1ki = w1li + 256 * 256;
    u16* w2i  = w1ki + 256 * 256;
    u16* w3i  = w2i + 256 * 256;
    float* part = (float*)(w3i + 256 * 256); // [8*625][256] = 5.12 MB

    hipLaunchKernelGGL(k_prep, dim3(1536), dim3(256), 0, stream,
                       pw, pwi, w1, w1li, w1ki, w2, w2i, w3, w3i);
    hipLaunchKernelGGL(k_xa3, dim3(14, 8), dim3(256), 0, stream,
                       im, pwi, pb, w1li, w1ki, al, ak);
    hipLaunchKernelGGL(k_main7, dim3(kLC, kKC, 8), dim3(256), 0, stream,
                       ak, al, b1, w2i, b2, w3i, b3, part);
    hipLaunchKernelGGL(k_reduce, dim3(8), dim3(1024), 0, stream, part, out);
}